// Round 3
// baseline (597.494 us; speedup 1.0000x reference)
//
#include <hip/hip_runtime.h>
#include <stdint.h>

// Problem: KS=3, ST=2, PAD=1, H=W=28, C=768, NH=12, hh=ww=14, dh=64.
// Inputs fp32 (confirmed: bf16 reinterpretation in R1 produced NaN -> full
// fp32 mantissas). Output fp32 (reference output dtype; R2's bf16-packed
// write half-filled the buffer -> error ~ max|ref|, the fp32-readback
// signature). Accumulate fp32, store fp32.
#define HOUT 28
#define HH   14
#define NHEADS 12
#define CC   768

// Gather formulation (each mm element folds into exactly ONE output pixel):
//   out[b,y,x,c] = sum over (kh,kw) with 2h+kh = y+1, 2w+kw = x+1,
//                  h,w in [0,14), kh,kw in {0,1,2}:
//                  sum_{qh,qw} attn[b,h,w,n,3kh+kw,3qh+qw] *
//                              vv[b, y-kh+qh, x-kw+qw, c]
// vv reads outside [0,28)^2 are the zero padding -> skipped. Every output
// element is written exactly once -> no atomics, no init needed.
__global__ __launch_bounds__(192)
void UnfoldMatmulFold_kernel(const float* __restrict__ vv,
                             const float* __restrict__ attn,
                             float* __restrict__ out)
{
    const int x   = blockIdx.x;      // 0..27
    const int y   = blockIdx.y;      // 0..27
    const int b   = blockIdx.z;
    const int tid = threadIdx.x;     // 0..191
    const int c4  = tid << 2;        // 4 channels per thread
    const int n   = c4 >> 6;         // head index (64 ch/head)

    const int ypad = y + 1;          // row in padded(30) space = 2h + kh
    const int xpad = x + 1;

    int khs[2]; int nkh = 0;
    if (ypad & 1) { khs[nkh++] = 1; }
    else {
        if (ypad <= 26) khs[nkh++] = 0;   // h = ypad/2 <= 13
        khs[nkh++] = 2;                   // h = ypad/2 - 1 >= 0 (ypad even >= 2)
    }
    int kws[2]; int nkw = 0;
    if (xpad & 1) { kws[nkw++] = 1; }
    else {
        if (xpad <= 26) kws[nkw++] = 0;
        kws[nkw++] = 2;
    }

    const float* vb = vv + ((size_t)b * HOUT * HOUT * CC) + c4;

    float acc0 = 0.f, acc1 = 0.f, acc2 = 0.f, acc3 = 0.f;

    for (int i = 0; i < nkh; ++i) {
        const int kh = khs[i];
        const int h  = (ypad - kh) >> 1;
        for (int j = 0; j < nkw; ++j) {
            const int kw = kws[j];
            const int w  = (xpad - kw) >> 1;
            // attn[b,h,w,n,p,q], p = 3*kh+kw, q = 3*qh+qw
            const float* ap =
                attn + ((((((size_t)b * HH + h) * HH + w) * NHEADS + n) * 9
                         + (3 * kh + kw)) * 9);
            #pragma unroll
            for (int qh = 0; qh < 3; ++qh) {
                const int vrow = y - kh + qh;
                if ((unsigned)vrow >= HOUT) continue;   // zero padding
                #pragma unroll
                for (int qw = 0; qw < 3; ++qw) {
                    const int vcol = x - kw + qw;
                    if ((unsigned)vcol >= HOUT) continue;
                    const float a = ap[3 * qh + qw];
                    const float4 u = *(const float4*)
                        (vb + ((size_t)(vrow * HOUT + vcol)) * CC);
                    acc0 = fmaf(a, u.x, acc0);
                    acc1 = fmaf(a, u.y, acc1);
                    acc2 = fmaf(a, u.z, acc2);
                    acc3 = fmaf(a, u.w, acc3);
                }
            }
        }
    }

    const size_t oidx = (((size_t)b * HOUT + y) * HOUT + x) * CC + c4;
    float4 o;
    o.x = acc0; o.y = acc1; o.z = acc2; o.w = acc3;
    *(float4*)&out[oidx] = o;
}

extern "C" void kernel_launch(void* const* d_in, const int* in_sizes, int n_in,
                              void* d_out, int out_size, void* d_ws, size_t ws_size,
                              hipStream_t stream) {
    const float* vv   = (const float*)d_in[0];
    const float* attn = (const float*)d_in[1];
    float* out        = (float*)d_out;

    const int B = in_sizes[0] / (HOUT * HOUT * CC);   // 64
    dim3 grid(HOUT, HOUT, B);
    UnfoldMatmulFold_kernel<<<grid, 192, 0, stream>>>(vv, attn, out);
}

// Round 4
// 470.283 us; speedup vs baseline: 1.2705x; 1.2705x over previous
//
#include <hip/hip_runtime.h>
#include <stdint.h>

// Problem: KS=3, ST=2, PAD=1, H=W=28, C=768, NH=12, hh=ww=14, dh=64.
// Inputs fp32, output fp32 (confirmed R1-R3). Accumulate fp32.
//
// R3 counters: WRITE ideal, FETCH 6.2x over-fetch (= 8 XCDs each streaming
// the whole vv through a private 4 MB L2). Fix: XCD-aware block swizzle --
// 1-D grid decoded so (id & 7) == (b & 7): under round-robin block->XCD
// dispatch each image (3.2 MB working set: 2.4 MB vv + 0.77 MB attn) stays
// resident in ONE XCD's L2 and is fetched from HBM once. Heuristic only;
// correctness does not depend on the mapping.
#define HOUT 28
#define HH   14
#define NHEADS 12
#define CC   768
#define NPIX (HOUT * HOUT)   // 784

// Gather formulation (each mm element folds into exactly ONE output pixel):
//   out[b,y,x,c] = sum over (kh,kw) with 2h+kh = y+1, 2w+kw = x+1,
//                  h,w in [0,14), kh,kw in {0,1,2}:
//                  sum_{qh,qw} attn[b,h,w,n,3kh+kw,3qh+qw] *
//                              vv[b, y-kh+qh, x-kw+qw, c]
// vv reads outside [0,28)^2 are zero padding -> skipped. Every output
// element is written exactly once -> no atomics, no init needed.
__global__ __launch_bounds__(192)
void UnfoldMatmulFold_kernel(const float* __restrict__ vv,
                             const float* __restrict__ attn,
                             float* __restrict__ out)
{
    // XCD-aware swizzle: id = (((bgrp*NPIX) + pix) << 3) | xcd
    // -> xcd = id & 7 (round-robin XCD), b = (bgrp << 3) | xcd,
    //    pixels of one image processed consecutively within an XCD.
    const unsigned id   = blockIdx.x;
    const unsigned xcd  = id & 7u;
    const unsigned j    = id >> 3;          // 0 .. 8*784-1
    const unsigned bgrp = j / NPIX;         // 0..7
    const unsigned pix  = j - bgrp * NPIX;  // 0..783
    const int b = (int)((bgrp << 3) | xcd);
    const int y = (int)(pix / HOUT);
    const int x = (int)(pix - (unsigned)y * HOUT);

    const int tid = threadIdx.x;     // 0..191
    const int c4  = tid << 2;        // 4 channels per thread
    const int n   = c4 >> 6;         // head index (64 ch/head)

    const int ypad = y + 1;          // row in padded(30) space = 2h + kh
    const int xpad = x + 1;

    int khs[2]; int nkh = 0;
    if (ypad & 1) { khs[nkh++] = 1; }
    else {
        if (ypad <= 26) khs[nkh++] = 0;   // h = ypad/2 <= 13
        khs[nkh++] = 2;                   // h = ypad/2 - 1 >= 0 (ypad even >= 2)
    }
    int kws[2]; int nkw = 0;
    if (xpad & 1) { kws[nkw++] = 1; }
    else {
        if (xpad <= 26) kws[nkw++] = 0;
        kws[nkw++] = 2;
    }

    const float* vb = vv + ((size_t)b * NPIX * CC) + c4;

    float acc0 = 0.f, acc1 = 0.f, acc2 = 0.f, acc3 = 0.f;

    for (int i = 0; i < nkh; ++i) {
        const int kh = khs[i];
        const int h  = (ypad - kh) >> 1;
        for (int j2 = 0; j2 < nkw; ++j2) {
            const int kw = kws[j2];
            const int w  = (xpad - kw) >> 1;
            // attn[b,h,w,n,p,q], p = 3*kh+kw, q = 3*qh+qw
            const float* ap =
                attn + ((((((size_t)b * HH + h) * HH + w) * NHEADS + n) * 9
                         + (3 * kh + kw)) * 9);
            #pragma unroll
            for (int qh = 0; qh < 3; ++qh) {
                const int vrow = y - kh + qh;
                if ((unsigned)vrow >= HOUT) continue;   // zero padding
                #pragma unroll
                for (int qw = 0; qw < 3; ++qw) {
                    const int vcol = x - kw + qw;
                    if ((unsigned)vcol >= HOUT) continue;
                    const float a = ap[3 * qh + qw];
                    const float4 u = *(const float4*)
                        (vb + ((size_t)(vrow * HOUT + vcol)) * CC);
                    acc0 = fmaf(a, u.x, acc0);
                    acc1 = fmaf(a, u.y, acc1);
                    acc2 = fmaf(a, u.z, acc2);
                    acc3 = fmaf(a, u.w, acc3);
                }
            }
        }
    }

    const size_t oidx = (((size_t)b * HOUT + y) * HOUT + x) * CC + c4;
    float4 o;
    o.x = acc0; o.y = acc1; o.z = acc2; o.w = acc3;
    *(float4*)&out[oidx] = o;
}

extern "C" void kernel_launch(void* const* d_in, const int* in_sizes, int n_in,
                              void* d_out, int out_size, void* d_ws, size_t ws_size,
                              hipStream_t stream) {
    const float* vv   = (const float*)d_in[0];
    const float* attn = (const float*)d_in[1];
    float* out        = (float*)d_out;

    const int B = in_sizes[0] / (NPIX * CC);   // 64
    dim3 grid((unsigned)(B * NPIX));           // 50176 blocks, 1-D swizzled
    UnfoldMatmulFold_kernel<<<grid, 192, 0, stream>>>(vv, attn, out);
}